// Round 9
// baseline (132.049 us; speedup 1.0000x reference)
//
#include <hip/hip_runtime.h>

// MHA forward, MI355X gfx950. bf16 MFMA pipeline, fp32 accumulate.
// Stages: cvt(fp32->bf16) -> fused QKV gemm_bt -> flash attention v9
//         (parity split-KV, 2 tiles/parity/barrier, static bin-packed single
//          round) -> out-proj gemm_bt (64x128 tiles).

#define DM   768
#define SEQ  2048
#define NB   2
#define NH   12
#define DK   64
#define MROWS (NB*SEQ)                       // 4096
#define QSCALE 0.18033688011112042f          // (1/sqrt(64)) * log2(e): softmax in exp2 domain

typedef unsigned short u16;
typedef __bf16 bf16x8 __attribute__((ext_vector_type(8)));
typedef float  f32x4  __attribute__((ext_vector_type(4)));
typedef unsigned int u32x4 __attribute__((ext_vector_type(4)));

__device__ __forceinline__ u16 f2bf(float f) {      // RNE f32 -> bf16
  unsigned u = __builtin_bit_cast(unsigned, f);
  u += 0x7fffu + ((u >> 16) & 1u);
  return (u16)(u >> 16);
}

__device__ __forceinline__ unsigned cvtpk(float lo, float hi) {  // 2xbf16 pack, RNE
  unsigned r;
  asm("v_cvt_pk_bf16_f32 %0, %1, %2" : "=v"(r) : "v"(lo), "v"(hi));
  return r;
}

__device__ __forceinline__ bf16x8 ldbf8(const u16* p) {   // 16B aligned load
  return __builtin_bit_cast(bf16x8, *(const u32x4*)p);
}

__device__ __forceinline__ void gl_lds16(const void* g, void* l) {
  __builtin_amdgcn_global_load_lds((__attribute__((address_space(1))) void*)g,
                                   (__attribute__((address_space(3))) void*)l,
                                   16, 0, 0);
}

// ---------------- fp32 -> bf16 converts ----------------
__global__ void cvt_bf16(const float* __restrict__ s, u16* __restrict__ d, int n4) {
  int i = blockIdx.x * blockDim.x + threadIdx.x;
  if (i < n4) {
    const float4 v = ((const float4*)s)[i];
    ushort4 r;
    r.x = f2bf(v.x); r.y = f2bf(v.y); r.z = f2bf(v.z); r.w = f2bf(v.w);
    ((ushort4*)d)[i] = r;
  }
}

__global__ void cvt_w4(const float* __restrict__ s0, const float* __restrict__ s1,
                       const float* __restrict__ s2, const float* __restrict__ s3,
                       u16* __restrict__ d, int n4) {
  const int i = blockIdx.x * blockDim.x + threadIdx.x;
  const int m = i / n4, r = i - m * n4;
  const float* s = (m == 0) ? s0 : (m == 1) ? s1 : (m == 2) ? s2 : s3;
  const float4 v = ((const float4*)s)[r];
  ushort4 rr;
  rr.x = f2bf(v.x); rr.y = f2bf(v.y); rr.z = f2bf(v.z); rr.w = f2bf(v.w);
  ((ushort4*)d)[i] = rr;
}

// ---------------- gemm_bt: C[m][n] = sum_k A[m][k]*B[n][k] ----------------
// TM x 128 tile, 2-deep pipelined (3 LDS buffer sets, counted vmcnt), linear
// grid with XCD-clustered decode. EPI0: TM=128, grid 576 (8 xcd x 4 bm x 18
// bn) -> 3 blocks/CU single round. EPI1: TM=64, grid 384 (8 x 8 bm x 6 bn).
template <int EPI, int TM>
__global__ __launch_bounds__(256, 3) void gemm_bt(
    const u16* __restrict__ A,
    const u16* __restrict__ B0, const u16* __restrict__ B1, const u16* __restrict__ B2,
    const float* __restrict__ bias0, const float* __restrict__ bias1, const float* __restrict__ bias2,
    u16* __restrict__ q_out, u16* __restrict__ k_out, u16* __restrict__ vt_out,
    float* __restrict__ f_out)
{
  constexpr int MF = TM / 32;                   // acc frags in M per wave
  __shared__ u16 At[3][TM*32];
  __shared__ u16 Bt[3][128*32];
  const int tid = threadIdx.x;
  const int w = tid >> 6, lane = tid & 63;
  const int lg = lane >> 4, ll = lane & 15;

  const int L = blockIdx.x;
  const int xcd = L & 7, li = L >> 3;
  int bm, bn;
  if (EPI == 0) { bm = xcd*4 + li/18; bn = li%18; }    // 32 bm, 18 bn
  else          { bm = xcd*8 + li/6;  bn = li%6;  }    // 64 bm, 6 bn
  const int row0 = bm * TM;

  const u16* Bm; const float* bias; int col0; int mat = 0;
  if (EPI == 0) {
    mat  = bn / 6;                               // 0=Q 1=K 2=V
    Bm   = (mat == 0) ? B0 : (mat == 1) ? B1 : B2;
    bias = (mat == 0) ? bias0 : (mat == 1) ? bias1 : bias2;
    col0 = (bn % 6) * 128;
  } else {
    Bm = B0; bias = bias0; col0 = bn * 128;
  }
  const int wr = w >> 1, wc = w & 1;

  f32x4 acc[MF][4] = {};

#define GSTAGE(BUF, K0) do {                                                  \
    _Pragma("unroll")                                                         \
    for (int c = w; c < TM/16; c += 4) {                                      \
      const int a = c*1024 + lane*16;                                         \
      gl_lds16((const char*)A + ((size_t)(row0 + (a>>6))*DM + (K0))*2 + (a&63), \
               (char*)At[BUF] + c*1024);                                      \
    }                                                                         \
    _Pragma("unroll")                                                         \
    for (int c = w; c < 8; c += 4) {                                          \
      const int a = c*1024 + lane*16;                                         \
      gl_lds16((const char*)Bm + ((size_t)(col0 + (a>>6))*DM + (K0))*2 + (a&63), \
               (char*)Bt[BUF] + c*1024);                                      \
    }                                                                         \
  } while (0)

  GSTAGE(0, 0);
  GSTAGE(1, 32);
  int cur = 0;
  const int nsteps = DM / 32;                    // 24
#pragma unroll 1
  for (int j = 0; j < nsteps; ++j) {
    if (j + 1 < nsteps) {
      if constexpr (TM == 128) asm volatile("s_waitcnt vmcnt(4)" ::: "memory");
      else                     asm volatile("s_waitcnt vmcnt(3)" ::: "memory");
    } else {
      asm volatile("s_waitcnt vmcnt(0)" ::: "memory");
    }
    __builtin_amdgcn_s_barrier();
    __builtin_amdgcn_sched_barrier(0);
    if (j + 2 < nsteps) {
      int nb = cur + 2; if (nb >= 3) nb -= 3;
      GSTAGE(nb, (j + 2) * 32);
    }

    bf16x8 fa[MF], fb[4];
#pragma unroll
    for (int m = 0; m < MF; ++m)
      fa[m] = ldbf8(&At[cur][(wr*(TM/2) + m*16 + ll)*32 + lg*8]);
#pragma unroll
    for (int n = 0; n < 4; ++n)
      fb[n] = ldbf8(&Bt[cur][(wc*64 + n*16 + ll)*32 + lg*8]);
#pragma unroll
    for (int m = 0; m < MF; ++m)
#pragma unroll
      for (int n = 0; n < 4; ++n)
        acc[m][n] = __builtin_amdgcn_mfma_f32_16x16x32_bf16(fa[m], fb[n], acc[m][n], 0, 0, 0);
    cur = (cur == 2) ? 0 : cur + 1;
  }
#undef GSTAGE

#pragma unroll
  for (int m = 0; m < MF; ++m) {
#pragma unroll
    for (int n = 0; n < 4; ++n) {
      const int gn  = col0 + wc*64 + n*16 + ll;
      const float bv = bias[gn];
      const int gm0 = row0 + wr*(TM/2) + m*16 + lg*4;
#pragma unroll
      for (int j = 0; j < 4; ++j) {
        const float v = acc[m][n][j] + bv;
        const int gm = gm0 + j;
        if (EPI == 0) {
          const int b = gm >> 11, s = gm & 2047;
          const int h = gn >> 6,  d = gn & 63;
          const size_t bh = (size_t)(b*NH + h);
          if (mat == 0)      q_out[(bh*SEQ + s)*DK + d] = f2bf(v * QSCALE);
          else if (mat == 1) k_out[(bh*SEQ + s)*DK + d] = f2bf(v);
          else               vt_out[(bh*DK + d)*SEQ + s] = f2bf(v);
        } else {
          f_out[(size_t)gm*DM + gn] = v;
        }
      }
    }
  }
}

// ---------------- flash attention v9 ----------------
// grid 512 = 8 XCD x 64 bins, exactly 2 blocks/CU -> single full-occupancy
// round. Each XCD owns 3 bh (KV L2-resident). Per-XCD, 192 jobs (3 bh x 64
// 32-row q-tiles, cost ceil(nt/4) iters each) are packed into 64 bins of
// 12-14 iters by a closed-form table: bins 0-23 {s8,s6}, 24-47 {s7,s5,s1},
// 48-59 {s4,s4,s3,s3}, 60-63 {6 x s2}, where size-class s covers nt in
// [4s-3, 4s] (tiles 2(nt-1), 2(nt-1)+1).
// Block = 4 waves: r = w&1 row-chunk (16 rows), h = w>>1 KV parity. Per
// barrier-iter parity h computes tiles 4i+2h, 4i+2h+1 (double-buffered LDS
// via async gl_lds, stage next pair after barrier). Swapped QK^T; defer-max
// (thr=8); per-lane partial l; parity merge through LDS arena.

__device__ __forceinline__ void stage_kv(const u16* kp, const u16* vp, int kv0,
                                         u16* Kb, u16* Vb, int r, int lane) {
  const char* kg = (const char*)kp + (size_t)kv0 * 128;   // K rows contiguous
  const char* vg = (const char*)vp + (size_t)kv0 * 2;     // V^T rows stride 4096B
#pragma unroll
  for (int j = 0; j < 4; ++j) {
    const int base = (r*4 + j) * 1024;          // wave-uniform base; HW adds lane*16
    const int a = base + lane*16;
    const int row = a >> 7;
    const int cs  = ((a >> 4) & 7) ^ (row & 7);
    gl_lds16(kg + row*128 + cs*16, (char*)Kb + base);
    gl_lds16(vg + (size_t)row*4096 + cs*16, (char*)Vb + base);
  }
}

__device__ __forceinline__ bf16x8 ldtile(const u16* T, int row, int wo) {
  return ldbf8((const u16*)((const char*)T + row*128 + (wo ^ ((row & 7) << 4))));
}

__global__ __launch_bounds__(256, 2) void attn_fwd(
    const u16* __restrict__ qb, const u16* __restrict__ kb,
    const u16* __restrict__ vtb, u16* __restrict__ attb)
{
  __shared__ u16 KVb[2][2][2][2][64*64];        // [parity][dbuf][sub][K|V] 64KB
  __shared__ __align__(16) char arena[9216];    // P repack / merge
  const int L = blockIdx.x;
  const int xcd = L & 7, bin = L >> 3;           // 0..63
  const int tid = threadIdx.x;
  const int w = tid >> 6, lane = tid & 63;
  const int r = w & 1, h = w >> 1;               // row-chunk, KV-parity
  const int lg = lane >> 4, ll = lane & 15;
  u16* Pl = (u16*)(arena + w*2304);
  float* mg = (float*)(arena + r*4608) + lane*18;

  // closed-form bin table: job = (bh_local<<6)|tile packed 8b each
  auto enc = [](int s, int j) -> unsigned long long {
    const int jj = j & 7, bl = j >> 3;
    const int k = 4*(s-1) + 1 + (jj >> 1);       // nt
    const int tile = 2*(k-1) + (jj & 1);
    return (unsigned long long)((bl << 6) | tile);
  };
  unsigned long long pack;
  int njobs;
  if (bin < 24)      { njobs = 2; pack = enc(8,bin) | (enc(6,bin) << 8); }
  else if (bin < 48) { const int j = bin-24; njobs = 3;
                       pack = enc(7,j) | (enc(5,j) << 8) | (enc(1,j) << 16); }
  else if (bin < 60) { const int j = bin-48; njobs = 4;
                       pack = enc(4,2*j) | (enc(4,2*j+1) << 8)
                            | (enc(3,2*j) << 16) | (enc(3,2*j+1) << 24); }
  else               { const int j = bin-60; njobs = 6; pack = 0;
#pragma unroll
                       for (int q = 0; q < 6; ++q)
                         pack |= enc(2, 6*j+q) << (8*q); }

#pragma unroll 1
  for (int job = 0; job < njobs; ++job) {
    const int e = (int)((pack >> (8*job)) & 255);
    const int bh = xcd*3 + (e >> 6);
    const int tile = e & 63;
    const u16* qp = qb  + (size_t)bh * SEQ * DK;
    const u16* kp = kb  + (size_t)bh * SEQ * DK;
    const u16* vp = vtb + (size_t)bh * DK * SEQ;
    const int bb = bh / NH, hh = bh % NH;
    const int nt = (tile >> 1) + 1;              // KV tiles (causal)
    const int nI = (nt + 3) >> 2;                // barrier-iters
    const int q0 = tile * 32 + r * 16;

    const bf16x8 qf0 = ldbf8(&qp[(size_t)(q0 + ll)*DK + lg*8]);
    const bf16x8 qf1 = ldbf8(&qp[(size_t)(q0 + ll)*DK + 32 + lg*8]);

    f32x4 o[4] = {};
    float mrun = 0.f, lrun = 0.f;                // m=0 valid: defer-thr bounds P<=2^8

    // prologue: stage this parity's first tile pair into dbuf 0
    if (2*h     < nt) stage_kv(kp, vp, (2*h)*64,   KVb[h][0][0][0], KVb[h][0][0][1], r, lane);
    if (2*h + 1 < nt) stage_kv(kp, vp, (2*h+1)*64, KVb[h][0][1][0], KVb[h][0][1][1], r, lane);

#pragma unroll 1
    for (int i = 0; i < nI; ++i) {
      asm volatile("s_waitcnt vmcnt(0)" ::: "memory");
      __builtin_amdgcn_s_barrier();              // all waves' stage(i) landed
      __builtin_amdgcn_sched_barrier(0);
      const int tb = 4*i;
      const int tn = tb + 4 + 2*h;               // next iter's pair
      if (tn     < nt) stage_kv(kp, vp, tn*64,     KVb[h][(i+1)&1][0][0], KVb[h][(i+1)&1][0][1], r, lane);
      if (tn + 1 < nt) stage_kv(kp, vp, (tn+1)*64, KVb[h][(i+1)&1][1][0], KVb[h][(i+1)&1][1][1], r, lane);

#pragma unroll
      for (int s = 0; s < 2; ++s) {
        const int t = tb + 2*h + s;
        if (t < nt) {
          const u16* Kc = KVb[h][i&1][s][0];
          const u16* Vc = KVb[h][i&1][s][1];

          f32x4 st[4] = {};
          __builtin_amdgcn_s_setprio(1);
#pragma unroll
          for (int kt = 0; kt < 4; ++kt) {
            const int rr = kt*16 + ll;
            st[kt] = __builtin_amdgcn_mfma_f32_16x16x32_bf16(ldtile(Kc, rr, lg*16),      qf0, st[kt], 0,0,0);
            st[kt] = __builtin_amdgcn_mfma_f32_16x16x32_bf16(ldtile(Kc, rr, 64 + lg*16), qf1, st[kt], 0,0,0);
          }
          __builtin_amdgcn_s_setprio(0);
          if (t == nt - 1) {                     // diagonal tile: causal mask
            const int kvb = t*64;
#pragma unroll
            for (int kt = 0; kt < 4; ++kt)
#pragma unroll
              for (int j = 0; j < 4; ++j)
                if (kvb + kt*16 + lg*4 + j > q0 + ll) st[kt][j] = -1e30f;
          }

          float lm = -1e30f;
#pragma unroll
          for (int kt = 0; kt < 4; ++kt)
            lm = fmaxf(lm, fmaxf(fmaxf(st[kt][0], st[kt][1]), fmaxf(st[kt][2], st[kt][3])));

          if (!__all(lm <= mrun + 8.f)) {        // rare: real max growth -> rescale
            float mt = lm;
            mt = fmaxf(mt, __shfl_xor(mt, 16));
            mt = fmaxf(mt, __shfl_xor(mt, 32));
            const float mn = fmaxf(mrun, mt);
            const float sc = exp2f(mrun - mn);
            lrun *= sc;
#pragma unroll
            for (int dt = 0; dt < 4; ++dt)
#pragma unroll
              for (int j = 0; j < 4; ++j)
                o[dt][j] *= sc;
            mrun = mn;
          }

          float psum = 0.f;
          unsigned pd[8];
#pragma unroll
          for (int kt = 0; kt < 4; ++kt) {
            const float e0 = exp2f(st[kt][0] - mrun);
            const float e1 = exp2f(st[kt][1] - mrun);
            const float e2 = exp2f(st[kt][2] - mrun);
            const float e3 = exp2f(st[kt][3] - mrun);
            psum += (e0 + e1) + (e2 + e3);
            pd[kt*2]   = cvtpk(e0, e1);
            pd[kt*2+1] = cvtpk(e2, e3);
          }
          lrun += psum;

#pragma unroll
          for (int kt = 0; kt < 4; ++kt)
            *(uint2*)&Pl[ll*72 + kt*16 + lg*4] = make_uint2(pd[kt*2], pd[kt*2+1]);
          const bf16x8 pb0 = ldbf8(&Pl[ll*72 + lg*8]);
          const bf16x8 pb1 = ldbf8(&Pl[ll*72 + 32 + lg*8]);

          __builtin_amdgcn_s_setprio(1);
#pragma unroll
          for (int dt = 0; dt < 4; ++dt) {
            const int rr = dt*16 + ll;
            o[dt] = __builtin_amdgcn_mfma_f32_16x16x32_bf16(ldtile(Vc, rr, lg*16),      pb0, o[dt], 0,0,0);
            o[dt] = __builtin_amdgcn_mfma_f32_16x16x32_bf16(ldtile(Vc, rr, 64 + lg*16), pb1, o[dt], 0,0,0);
          }
          __builtin_amdgcn_s_setprio(0);
        }
      }
    }

    // per-parity row totals
    float lt = lrun;
    lt += __shfl_xor(lt, 16);
    lt += __shfl_xor(lt, 32);

    // merge parity partials: h=1 publishes, h=0 merges + stores
    __syncthreads();                             // all KV/P reads done; arena free
    if (h == 1) {
#pragma unroll
      for (int dt = 0; dt < 4; ++dt)
#pragma unroll
        for (int j = 0; j < 4; ++j)
          mg[dt*4 + j] = o[dt][j];
      mg[16] = mrun;
      mg[17] = lt;
    }
    __syncthreads();
    if (h == 0) {
      const float mB = mg[16], lB = mg[17];
      const float ms = fmaxf(mrun, mB);
      const float sA = exp2f(mrun - ms), sB = exp2f(mB - ms);
      const float li = 1.0f / (lt * sA + lB * sB);
      u16* orow = &attb[(size_t)(bb*SEQ + q0 + ll)*DM + hh*64];
#pragma unroll
      for (int dt = 0; dt < 4; ++dt) {
        ushort4 rw;
        rw.x = f2bf((o[dt][0]*sA + mg[dt*4+0]*sB) * li);
        rw.y = f2bf((o[dt][1]*sA + mg[dt*4+1]*sB) * li);
        rw.z = f2bf((o[dt][2]*sA + mg[dt*4+2]*sB) * li);
        rw.w = f2bf((o[dt][3]*sA + mg[dt*4+3]*sB) * li);
        *(ushort4*)&orow[dt*16 + lg*4] = rw;
      }
    }
    __syncthreads();                             // arena + KV bufs free for next job
  }
}

// ---------------- launch ----------------
extern "C" void kernel_launch(void* const* d_in, const int* in_sizes, int n_in,
                              void* d_out, int out_size, void* d_ws, size_t ws_size,
                              hipStream_t stream) {
  const float* x  = (const float*)d_in[0];
  const float* wq = (const float*)d_in[1];
  const float* bq = (const float*)d_in[2];
  const float* wk = (const float*)d_in[3];
  const float* bk = (const float*)d_in[4];
  const float* wv = (const float*)d_in[5];
  const float* bv = (const float*)d_in[6];
  const float* wo = (const float*)d_in[7];
  const float* bo = (const float*)d_in[8];
  float* out = (float*)d_out;

  char* ws = (char*)d_ws;
  u16* xb   = (u16*)(ws);               // [4096][768]
  u16* wqb  = (u16*)(ws + 6291456);     // [768][768] x4 contiguous (wq,wk,wv,wo)
  u16* wkb  = (u16*)(ws + 7471104);
  u16* wvb  = (u16*)(ws + 8650752);
  u16* wob  = (u16*)(ws + 9830400);
  u16* qb   = (u16*)(ws + 11010048);    // [24][2048][64] scaled
  u16* kb   = (u16*)(ws + 17301504);    // [24][2048][64]
  u16* vtb  = (u16*)(ws + 23592960);    // [24][64][2048]
  u16* attb = (u16*)(ws + 29884416);    // [4096][768]

  const int nx4 = MROWS*DM/4;           // 786432
  const int nw4 = DM*DM/4;              // 147456
  cvt_bf16<<<(nx4+255)/256, 256, 0, stream>>>(x, xb, nx4);
  cvt_w4<<<(4*nw4)/256, 256, 0, stream>>>(wq, wk, wv, wo, wqb, nw4);

  gemm_bt<0,128><<<576, 256, 0, stream>>>(xb, wqb, wkb, wvb, bq, bk, bv,
                                          qb, kb, vtb, nullptr);
  attn_fwd<<<512, 256, 0, stream>>>(qb, kb, vtb, attb);
  gemm_bt<1,64><<<384, 256, 0, stream>>>(attb, wob, nullptr, nullptr, bo, nullptr, nullptr,
                                         nullptr, nullptr, nullptr, out);
}

// Round 10
// 119.151 us; speedup vs baseline: 1.1083x; 1.1083x over previous
//
#include <hip/hip_runtime.h>

// MHA forward, MI355X gfx950. bf16 MFMA pipeline, fp32 accumulate.
// Stages: cvt(fp32->bf16) -> fused QKV gemm_bt (2-deep pipeline, XCD-decode)
//         -> flash attention v10 (parity x kv-half waves, halved ds_read)
//         -> out-proj gemm_bt (64x128).

#define DM   768
#define SEQ  2048
#define NB   2
#define NH   12
#define DK   64
#define MROWS (NB*SEQ)                       // 4096
#define QSCALE 0.18033688011112042f          // (1/sqrt(64)) * log2(e): softmax in exp2 domain

typedef unsigned short u16;
typedef __bf16 bf16x8 __attribute__((ext_vector_type(8)));
typedef float  f32x4  __attribute__((ext_vector_type(4)));
typedef unsigned int u32x4 __attribute__((ext_vector_type(4)));

__device__ __forceinline__ u16 f2bf(float f) {      // RNE f32 -> bf16
  unsigned u = __builtin_bit_cast(unsigned, f);
  u += 0x7fffu + ((u >> 16) & 1u);
  return (u16)(u >> 16);
}

__device__ __forceinline__ unsigned cvtpk(float lo, float hi) {  // 2xbf16 pack, RNE
  unsigned r;
  asm("v_cvt_pk_bf16_f32 %0, %1, %2" : "=v"(r) : "v"(lo), "v"(hi));
  return r;
}

__device__ __forceinline__ bf16x8 ldbf8(const u16* p) {   // 16B aligned load
  return __builtin_bit_cast(bf16x8, *(const u32x4*)p);
}

__device__ __forceinline__ void gl_lds16(const void* g, void* l) {
  __builtin_amdgcn_global_load_lds((__attribute__((address_space(1))) void*)g,
                                   (__attribute__((address_space(3))) void*)l,
                                   16, 0, 0);
}

// ---------------- fp32 -> bf16 converts ----------------
__global__ void cvt_bf16(const float* __restrict__ s, u16* __restrict__ d, int n4) {
  int i = blockIdx.x * blockDim.x + threadIdx.x;
  if (i < n4) {
    const float4 v = ((const float4*)s)[i];
    ushort4 r;
    r.x = f2bf(v.x); r.y = f2bf(v.y); r.z = f2bf(v.z); r.w = f2bf(v.w);
    ((ushort4*)d)[i] = r;
  }
}

__global__ void cvt_w4(const float* __restrict__ s0, const float* __restrict__ s1,
                       const float* __restrict__ s2, const float* __restrict__ s3,
                       u16* __restrict__ d, int n4) {
  const int i = blockIdx.x * blockDim.x + threadIdx.x;
  const int m = i / n4, r = i - m * n4;
  const float* s = (m == 0) ? s0 : (m == 1) ? s1 : (m == 2) ? s2 : s3;
  const float4 v = ((const float4*)s)[r];
  ushort4 rr;
  rr.x = f2bf(v.x); rr.y = f2bf(v.y); rr.z = f2bf(v.z); rr.w = f2bf(v.w);
  ((ushort4*)d)[i] = rr;
}

// ---------------- gemm_bt: C[m][n] = sum_k A[m][k]*B[n][k] (R9, kept) -------
template <int EPI, int TM>
__global__ __launch_bounds__(256, 3) void gemm_bt(
    const u16* __restrict__ A,
    const u16* __restrict__ B0, const u16* __restrict__ B1, const u16* __restrict__ B2,
    const float* __restrict__ bias0, const float* __restrict__ bias1, const float* __restrict__ bias2,
    u16* __restrict__ q_out, u16* __restrict__ k_out, u16* __restrict__ vt_out,
    float* __restrict__ f_out)
{
  constexpr int MF = TM / 32;
  __shared__ u16 At[3][TM*32];
  __shared__ u16 Bt[3][128*32];
  const int tid = threadIdx.x;
  const int w = tid >> 6, lane = tid & 63;
  const int lg = lane >> 4, ll = lane & 15;

  const int L = blockIdx.x;
  const int xcd = L & 7, li = L >> 3;
  int bm, bn;
  if (EPI == 0) { bm = xcd*4 + li/18; bn = li%18; }
  else          { bm = xcd*8 + li/6;  bn = li%6;  }
  const int row0 = bm * TM;

  const u16* Bm; const float* bias; int col0; int mat = 0;
  if (EPI == 0) {
    mat  = bn / 6;
    Bm   = (mat == 0) ? B0 : (mat == 1) ? B1 : B2;
    bias = (mat == 0) ? bias0 : (mat == 1) ? bias1 : bias2;
    col0 = (bn % 6) * 128;
  } else {
    Bm = B0; bias = bias0; col0 = bn * 128;
  }
  const int wr = w >> 1, wc = w & 1;

  f32x4 acc[MF][4] = {};

#define GSTAGE(BUF, K0) do {                                                  \
    _Pragma("unroll")                                                         \
    for (int c = w; c < TM/16; c += 4) {                                      \
      const int a = c*1024 + lane*16;                                         \
      gl_lds16((const char*)A + ((size_t)(row0 + (a>>6))*DM + (K0))*2 + (a&63), \
               (char*)At[BUF] + c*1024);                                      \
    }                                                                         \
    _Pragma("unroll")                                                         \
    for (int c = w; c < 8; c += 4) {                                          \
      const int a = c*1024 + lane*16;                                         \
      gl_lds16((const char*)Bm + ((size_t)(col0 + (a>>6))*DM + (K0))*2 + (a&63), \
               (char*)Bt[BUF] + c*1024);                                      \
    }                                                                         \
  } while (0)

  GSTAGE(0, 0);
  GSTAGE(1, 32);
  int cur = 0;
  const int nsteps = DM / 32;
#pragma unroll 1
  for (int j = 0; j < nsteps; ++j) {
    if (j + 1 < nsteps) {
      if constexpr (TM == 128) asm volatile("s_waitcnt vmcnt(4)" ::: "memory");
      else                     asm volatile("s_waitcnt vmcnt(3)" ::: "memory");
    } else {
      asm volatile("s_waitcnt vmcnt(0)" ::: "memory");
    }
    __builtin_amdgcn_s_barrier();
    __builtin_amdgcn_sched_barrier(0);
    if (j + 2 < nsteps) {
      int nb = cur + 2; if (nb >= 3) nb -= 3;
      GSTAGE(nb, (j + 2) * 32);
    }

    bf16x8 fa[MF], fb[4];
#pragma unroll
    for (int m = 0; m < MF; ++m)
      fa[m] = ldbf8(&At[cur][(wr*(TM/2) + m*16 + ll)*32 + lg*8]);
#pragma unroll
    for (int n = 0; n < 4; ++n)
      fb[n] = ldbf8(&Bt[cur][(wc*64 + n*16 + ll)*32 + lg*8]);
#pragma unroll
    for (int m = 0; m < MF; ++m)
#pragma unroll
      for (int n = 0; n < 4; ++n)
        acc[m][n] = __builtin_amdgcn_mfma_f32_16x16x32_bf16(fa[m], fb[n], acc[m][n], 0, 0, 0);
    cur = (cur == 2) ? 0 : cur + 1;
  }
#undef GSTAGE

#pragma unroll
  for (int m = 0; m < MF; ++m) {
#pragma unroll
    for (int n = 0; n < 4; ++n) {
      const int gn  = col0 + wc*64 + n*16 + ll;
      const float bv = bias[gn];
      const int gm0 = row0 + wr*(TM/2) + m*16 + lg*4;
#pragma unroll
      for (int j = 0; j < 4; ++j) {
        const float v = acc[m][n][j] + bv;
        const int gm = gm0 + j;
        if (EPI == 0) {
          const int b = gm >> 11, s = gm & 2047;
          const int h = gn >> 6,  d = gn & 63;
          const size_t bh = (size_t)(b*NH + h);
          if (mat == 0)      q_out[(bh*SEQ + s)*DK + d] = f2bf(v * QSCALE);
          else if (mat == 1) k_out[(bh*SEQ + s)*DK + d] = f2bf(v);
          else               vt_out[(bh*DK + d)*SEQ + s] = f2bf(v);
        } else {
          f_out[(size_t)gm*DM + gn] = v;
        }
      }
    }
  }
}

// ---------------- flash attention v10: parity x kv-half waves ----------------
// grid 768 (R8 decode: xcd=L&7, bh=xcd*3+rr0%3, pairb=rr0/3; halves {63-p,p}).
// Block = 4 waves: h = w>>1 tile parity, r = w&1 KV-HALF. Each wave covers all
// 32 q-rows (2 chunks of 16) x its 32-kv half -> K/V ds_read per wave HALVED
// (4+4 b128 vs 16), P read 1/chunk, K/V frags reused across chunks (2x ILP).
// Staging identical to R8 (async gl_lds, dbuf, vmcnt(0)+barrier per iter);
// wave (h,r) stages its K rows [r*32,+32) and V s-cols [r*32,+32) (s-half-
// contiguous V layout, chunk-XOR swizzle c^((row>>1)&3), both sides).
// Epilogue: 4-way f32 merge (half->parity->final) via time-shared arena.

__device__ __forceinline__ void stage_kv_half(const u16* kp, const u16* vp, int kv0,
                                              u16* Kb, u16* Vb, int r, int lane) {
  const char* kg = (const char*)kp + (size_t)kv0 * 128;   // K rows contiguous
  const char* vg = (const char*)vp + (size_t)kv0 * 2;     // V^T d-rows stride 4096B
#pragma unroll
  for (int j = 0; j < 4; ++j) {                 // K half: rows [r*32, r*32+32)
    const int base = (r*4 + j) * 1024;
    const int a = base + lane*16;
    const int row = a >> 7;                     // 128B rows
    const int cs  = ((a >> 4) & 7) ^ (row & 7);
    gl_lds16(kg + row*128 + cs*16, (char*)Kb + base);
  }
#pragma unroll
  for (int j = 0; j < 4; ++j) {                 // V half: [64 d][32 s] block at r*4096
    const int base = j * 1024;
    const int a = base + lane*16;
    const int row = a >> 6;                     // 64B rows (d)
    const int cs  = ((a >> 4) & 3) ^ ((row >> 1) & 3);
    gl_lds16(vg + (size_t)row*4096 + r*64 + cs*16, (char*)Vb + r*4096 + base);
  }
}

__device__ __forceinline__ bf16x8 ldtileK(const u16* T, int row, int wo) {
  return ldbf8((const u16*)((const char*)T + row*128 + (wo ^ ((row & 7) << 4))));
}
__device__ __forceinline__ bf16x8 ldtileV(const u16* T, int r, int row, int lg) {
  const int c = lg ^ ((row >> 1) & 3);
  return ldbf8((const u16*)((const char*)T + r*4096 + row*64 + c*16));
}

__global__ __launch_bounds__(256, 2) void attn_fwd(
    const u16* __restrict__ qb, const u16* __restrict__ kb,
    const u16* __restrict__ vtb, u16* __restrict__ attb)
{
  __shared__ u16 KVb[2][2][2][64*64];           // [parity][dbuf][K|V] = 64KB
  __shared__ __align__(16) char arena[9472];    // P repack (loop) / merge buf
  const int L = blockIdx.x;
  const int xcd = L & 7, rr0 = L >> 3;
  const int bh = xcd * 3 + (rr0 % 3);
  const int pairb = rr0 / 3;                    // 0..31
  const int tid = threadIdx.x;
  const int w = tid >> 6, lane = tid & 63;
  const int h = w >> 1, r = w & 1;              // tile parity, kv half
  const int lg = lane >> 4, ll = lane & 15;
  const u16* qp = qb  + (size_t)bh * SEQ * DK;
  const u16* kp = kb  + (size_t)bh * SEQ * DK;
  const u16* vp = vtb + (size_t)bh * DK * SEQ;
  const int bb = bh / NH, hh = bh % NH;
  u16* Pl = (u16*)(arena) + w*1152;             // per-wave 2304B: [2 chunk][16 q][72B]
  float* slot = (float*)(arena) + lane*37;      // merge buf (time-shared with Pl)

#pragma unroll 1
  for (int half = 0; half < 2; ++half) {
    const int tile = half ? pairb : 63 - pairb;  // 32-row q-tile
    const int nt = (tile >> 1) + 1;              // KV tiles (causal)
    const int q0b = tile * 32;

    bf16x8 qf[2][2];
#pragma unroll
    for (int c = 0; c < 2; ++c)
#pragma unroll
      for (int d = 0; d < 2; ++d)
        qf[c][d] = ldbf8(&qp[(size_t)(q0b + c*16 + ll)*DK + d*32 + lg*8]);

    f32x4 o[2][4] = {};                          // [chunk][dt]: O[q=c*16+ll][dt*16+lg*4+j]
    float mrun[2] = {0.f, 0.f}, lrun[2] = {0.f, 0.f};

    const int nI = (nt + 1) >> 1;
    if (h < nt) stage_kv_half(kp, vp, h*64, KVb[h][0][0], KVb[h][0][1], r, lane);

#pragma unroll 1
    for (int i = 0; i < nI; ++i) {
      const int t = h + 2*i;
      if (t < nt) asm volatile("s_waitcnt vmcnt(0)" ::: "memory");
      __builtin_amdgcn_s_barrier();
      __builtin_amdgcn_sched_barrier(0);
      if (t + 2 < nt)
        stage_kv_half(kp, vp, (t+2)*64, KVb[h][(i+1)&1][0], KVb[h][(i+1)&1][1], r, lane);

      if (t < nt) {
        const u16* Kc = KVb[h][i&1][0];
        const u16* Vc = KVb[h][i&1][1];
        const int kv0 = t * 64;

        // operand frags: own kv-half only (4 K + 4 V b128), reused across chunks
        bf16x8 Kf[2][2], Vf[4];
#pragma unroll
        for (int kt = 0; kt < 2; ++kt)
#pragma unroll
          for (int d = 0; d < 2; ++d)
            Kf[kt][d] = ldtileK(Kc, r*32 + kt*16 + ll, d*64 + lg*16);
#pragma unroll
        for (int dt = 0; dt < 4; ++dt)
          Vf[dt] = ldtileV(Vc, r, dt*16 + ll, lg);

        // S^T = K_half . Q^T : two independent chunk chains
        f32x4 st[2][2] = {};
        __builtin_amdgcn_s_setprio(1);
#pragma unroll
        for (int c = 0; c < 2; ++c)
#pragma unroll
          for (int kt = 0; kt < 2; ++kt) {
            st[c][kt] = __builtin_amdgcn_mfma_f32_16x16x32_bf16(Kf[kt][0], qf[c][0], st[c][kt], 0,0,0);
            st[c][kt] = __builtin_amdgcn_mfma_f32_16x16x32_bf16(Kf[kt][1], qf[c][1], st[c][kt], 0,0,0);
          }
        __builtin_amdgcn_s_setprio(0);

        if (t == nt - 1) {                       // diagonal: causal mask
          const int kvb = kv0 + r*32;
#pragma unroll
          for (int c = 0; c < 2; ++c)
#pragma unroll
            for (int kt = 0; kt < 2; ++kt)
#pragma unroll
              for (int j = 0; j < 4; ++j)
                if (kvb + kt*16 + lg*4 + j > q0b + c*16 + ll) st[c][kt][j] = -1e30f;
        }

        float lm[2];
#pragma unroll
        for (int c = 0; c < 2; ++c)
          lm[c] = fmaxf(fmaxf(fmaxf(st[c][0][0], st[c][0][1]), fmaxf(st[c][0][2], st[c][0][3])),
                        fmaxf(fmaxf(st[c][1][0], st[c][1][1]), fmaxf(st[c][1][2], st[c][1][3])));

        if (!__all(fmaxf(lm[0] - mrun[0], lm[1] - mrun[1]) <= 8.f)) {   // rare
#pragma unroll
          for (int c = 0; c < 2; ++c) {
            float mt = lm[c];
            mt = fmaxf(mt, __shfl_xor(mt, 16));
            mt = fmaxf(mt, __shfl_xor(mt, 32));
            const float mn = fmaxf(mrun[c], mt);
            const float sc = exp2f(mrun[c] - mn);
            lrun[c] *= sc;
#pragma unroll
            for (int dt = 0; dt < 4; ++dt)
#pragma unroll
              for (int j = 0; j < 4; ++j)
                o[c][dt][j] *= sc;
            mrun[c] = mn;
          }
        }

        bf16x8 pb[2];
#pragma unroll
        for (int c = 0; c < 2; ++c) {
          float psum = 0.f;
#pragma unroll
          for (int kt = 0; kt < 2; ++kt) {
            const float e0 = exp2f(st[c][kt][0] - mrun[c]);
            const float e1 = exp2f(st[c][kt][1] - mrun[c]);
            const float e2 = exp2f(st[c][kt][2] - mrun[c]);
            const float e3 = exp2f(st[c][kt][3] - mrun[c]);
            psum += (e0 + e1) + (e2 + e3);
            *(uint2*)&Pl[c*576 + ll*36 + kt*16 + lg*4] =
                make_uint2(cvtpk(e0, e1), cvtpk(e2, e3));
          }
          lrun[c] += psum;
          pb[c] = ldbf8(&Pl[c*576 + ll*36 + lg*8]);   // P[q=c*16+ll][kv lg*8..+7]
        }

        // O^T += V_half . P^T (K-dim = 32 = own kv half)
        __builtin_amdgcn_s_setprio(1);
#pragma unroll
        for (int c = 0; c < 2; ++c)
#pragma unroll
          for (int dt = 0; dt < 4; ++dt)
            o[c][dt] = __builtin_amdgcn_mfma_f32_16x16x32_bf16(Vf[dt], pb[c], o[c][dt], 0,0,0);
        __builtin_amdgcn_s_setprio(0);
      }
    }

    // per-wave row totals (sum lg partials of own kv subset)
    float lt[2];
#pragma unroll
    for (int c = 0; c < 2; ++c) {
      lt[c] = lrun[c];
      lt[c] += __shfl_xor(lt[c], 16);
      lt[c] += __shfl_xor(lt[c], 32);
    }

    // 4-way merge: (h0r0 <- h0r1), (h1r0 <- h1r1), (h0r0 <- h1r0), f32 exact
#define PUBLISH() do {                                                   \
      _Pragma("unroll")                                                  \
      for (int c = 0; c < 2; ++c)                                        \
        _Pragma("unroll")                                                \
        for (int dt = 0; dt < 4; ++dt)                                   \
          _Pragma("unroll")                                              \
          for (int j = 0; j < 4; ++j)                                    \
            slot[c*16 + dt*4 + j] = o[c][dt][j];                         \
      slot[32] = mrun[0]; slot[33] = mrun[1];                            \
      slot[34] = lt[0];   slot[35] = lt[1];                              \
    } while (0)
#define MERGE() do {                                                     \
      _Pragma("unroll")                                                  \
      for (int c = 0; c < 2; ++c) {                                      \
        const float mB = slot[32 + c], lB = slot[34 + c];                \
        const float ms = fmaxf(mrun[c], mB);                             \
        const float sA = exp2f(mrun[c] - ms), sB = exp2f(mB - ms);       \
        _Pragma("unroll")                                                \
        for (int dt = 0; dt < 4; ++dt)                                   \
          _Pragma("unroll")                                              \
          for (int j = 0; j < 4; ++j)                                    \
            o[c][dt][j] = o[c][dt][j]*sA + slot[c*16 + dt*4 + j]*sB;     \
        lt[c] = lt[c]*sA + lB*sB;                                        \
        mrun[c] = ms;                                                    \
      }                                                                  \
    } while (0)

    __syncthreads();                             // compute done; arena free
    if (w == 1) PUBLISH();
    __syncthreads();
    if (w == 0) MERGE();
    __syncthreads();                             // w0 reads done before w3 writes
    if (w == 3) PUBLISH();
    __syncthreads();
    if (w == 2) MERGE();
    __syncthreads();
    if (w == 2) PUBLISH();
    __syncthreads();
    if (w == 0) {
      MERGE();
#pragma unroll
      for (int c = 0; c < 2; ++c) {
        const float li = 1.0f / lt[c];
        u16* orow = &attb[(size_t)(bb*SEQ + q0b + c*16 + ll)*DM + hh*64];
#pragma unroll
        for (int dt = 0; dt < 4; ++dt) {
          ushort4 rw;
          rw.x = f2bf(o[c][dt][0] * li);
          rw.y = f2bf(o[c][dt][1] * li);
          rw.z = f2bf(o[c][dt][2] * li);
          rw.w = f2bf(o[c][dt][3] * li);
          *(ushort4*)&orow[dt*16 + lg*4] = rw;
        }
      }
    }
    __syncthreads();                             // arena + KV bufs free for next half
#undef PUBLISH
#undef MERGE
  }
}

// ---------------- launch ----------------
extern "C" void kernel_launch(void* const* d_in, const int* in_sizes, int n_in,
                              void* d_out, int out_size, void* d_ws, size_t ws_size,
                              hipStream_t stream) {
  const float* x  = (const float*)d_in[0];
  const float* wq = (const float*)d_in[1];
  const float* bq = (const float*)d_in[2];
  const float* wk = (const float*)d_in[3];
  const float* bk = (const float*)d_in[4];
  const float* wv = (const float*)d_in[5];
  const float* bv = (const float*)d_in[6];
  const float* wo = (const float*)d_in[7];
  const float* bo = (const float*)d_in[8];
  float* out = (float*)d_out;

  char* ws = (char*)d_ws;
  u16* xb   = (u16*)(ws);               // [4096][768]
  u16* wqb  = (u16*)(ws + 6291456);     // [768][768] x4 contiguous
  u16* wkb  = (u16*)(ws + 7471104);
  u16* wvb  = (u16*)(ws + 8650752);
  u16* wob  = (u16*)(ws + 9830400);
  u16* qb   = (u16*)(ws + 11010048);    // [24][2048][64] scaled
  u16* kb   = (u16*)(ws + 17301504);    // [24][2048][64]
  u16* vtb  = (u16*)(ws + 23592960);    // [24][64][2048]
  u16* attb = (u16*)(ws + 29884416);    // [4096][768]

  const int nx4 = MROWS*DM/4;
  const int nw4 = DM*DM/4;
  cvt_bf16<<<(nx4+255)/256, 256, 0, stream>>>(x, xb, nx4);
  cvt_w4<<<(4*nw4)/256, 256, 0, stream>>>(wq, wk, wv, wo, wqb, nw4);

  gemm_bt<0,128><<<576, 256, 0, stream>>>(xb, wqb, wkb, wvb, bq, bk, bv,
                                          qb, kb, vtb, nullptr);
  attn_fwd<<<768, 256, 0, stream>>>(qb, kb, vtb, attb);
  gemm_bt<1,64><<<384, 256, 0, stream>>>(attb, wob, nullptr, nullptr, bo, nullptr, nullptr,
                                         nullptr, nullptr, nullptr, out);
}

// Round 11
// 115.535 us; speedup vs baseline: 1.1429x; 1.0313x over previous
//
#include <hip/hip_runtime.h>

// MHA forward, MI355X gfx950. bf16 MFMA pipeline, fp32 accumulate.
// Stages: cvt(fp32->bf16) -> fused QKV gemm_bt (2-deep pipeline, XCD-decode)
//         -> flash attention v11 (parity x kv-half waves, BARRIER-FREE per-wave
//            pipelines with counted vmcnt) -> out-proj gemm_bt (64x128).

#define DM   768
#define SEQ  2048
#define NB   2
#define NH   12
#define DK   64
#define MROWS (NB*SEQ)                       // 4096
#define QSCALE 0.18033688011112042f          // (1/sqrt(64)) * log2(e): softmax in exp2 domain

typedef unsigned short u16;
typedef __bf16 bf16x8 __attribute__((ext_vector_type(8)));
typedef float  f32x4  __attribute__((ext_vector_type(4)));
typedef unsigned int u32x4 __attribute__((ext_vector_type(4)));

__device__ __forceinline__ u16 f2bf(float f) {      // RNE f32 -> bf16
  unsigned u = __builtin_bit_cast(unsigned, f);
  u += 0x7fffu + ((u >> 16) & 1u);
  return (u16)(u >> 16);
}

__device__ __forceinline__ unsigned cvtpk(float lo, float hi) {  // 2xbf16 pack, RNE
  unsigned r;
  asm("v_cvt_pk_bf16_f32 %0, %1, %2" : "=v"(r) : "v"(lo), "v"(hi));
  return r;
}

__device__ __forceinline__ bf16x8 ldbf8(const u16* p) {   // 16B aligned load
  return __builtin_bit_cast(bf16x8, *(const u32x4*)p);
}

__device__ __forceinline__ void gl_lds16(const void* g, void* l) {
  __builtin_amdgcn_global_load_lds((__attribute__((address_space(1))) void*)g,
                                   (__attribute__((address_space(3))) void*)l,
                                   16, 0, 0);
}

// ---------------- fp32 -> bf16 converts ----------------
__global__ void cvt_bf16(const float* __restrict__ s, u16* __restrict__ d, int n4) {
  int i = blockIdx.x * blockDim.x + threadIdx.x;
  if (i < n4) {
    const float4 v = ((const float4*)s)[i];
    ushort4 r;
    r.x = f2bf(v.x); r.y = f2bf(v.y); r.z = f2bf(v.z); r.w = f2bf(v.w);
    ((ushort4*)d)[i] = r;
  }
}

__global__ void cvt_w4(const float* __restrict__ s0, const float* __restrict__ s1,
                       const float* __restrict__ s2, const float* __restrict__ s3,
                       u16* __restrict__ d, int n4) {
  const int i = blockIdx.x * blockDim.x + threadIdx.x;
  const int m = i / n4, r = i - m * n4;
  const float* s = (m == 0) ? s0 : (m == 1) ? s1 : (m == 2) ? s2 : s3;
  const float4 v = ((const float4*)s)[r];
  ushort4 rr;
  rr.x = f2bf(v.x); rr.y = f2bf(v.y); rr.z = f2bf(v.z); rr.w = f2bf(v.w);
  ((ushort4*)d)[i] = rr;
}

// ---------------- gemm_bt: C[m][n] = sum_k A[m][k]*B[n][k] (R9, kept) -------
template <int EPI, int TM>
__global__ __launch_bounds__(256, 3) void gemm_bt(
    const u16* __restrict__ A,
    const u16* __restrict__ B0, const u16* __restrict__ B1, const u16* __restrict__ B2,
    const float* __restrict__ bias0, const float* __restrict__ bias1, const float* __restrict__ bias2,
    u16* __restrict__ q_out, u16* __restrict__ k_out, u16* __restrict__ vt_out,
    float* __restrict__ f_out)
{
  constexpr int MF = TM / 32;
  __shared__ u16 At[3][TM*32];
  __shared__ u16 Bt[3][128*32];
  const int tid = threadIdx.x;
  const int w = tid >> 6, lane = tid & 63;
  const int lg = lane >> 4, ll = lane & 15;

  const int L = blockIdx.x;
  const int xcd = L & 7, li = L >> 3;
  int bm, bn;
  if (EPI == 0) { bm = xcd*4 + li/18; bn = li%18; }
  else          { bm = xcd*8 + li/6;  bn = li%6;  }
  const int row0 = bm * TM;

  const u16* Bm; const float* bias; int col0; int mat = 0;
  if (EPI == 0) {
    mat  = bn / 6;
    Bm   = (mat == 0) ? B0 : (mat == 1) ? B1 : B2;
    bias = (mat == 0) ? bias0 : (mat == 1) ? bias1 : bias2;
    col0 = (bn % 6) * 128;
  } else {
    Bm = B0; bias = bias0; col0 = bn * 128;
  }
  const int wr = w >> 1, wc = w & 1;

  f32x4 acc[MF][4] = {};

#define GSTAGE(BUF, K0) do {                                                  \
    _Pragma("unroll")                                                         \
    for (int c = w; c < TM/16; c += 4) {                                      \
      const int a = c*1024 + lane*16;                                         \
      gl_lds16((const char*)A + ((size_t)(row0 + (a>>6))*DM + (K0))*2 + (a&63), \
               (char*)At[BUF] + c*1024);                                      \
    }                                                                         \
    _Pragma("unroll")                                                         \
    for (int c = w; c < 8; c += 4) {                                          \
      const int a = c*1024 + lane*16;                                         \
      gl_lds16((const char*)Bm + ((size_t)(col0 + (a>>6))*DM + (K0))*2 + (a&63), \
               (char*)Bt[BUF] + c*1024);                                      \
    }                                                                         \
  } while (0)

  GSTAGE(0, 0);
  GSTAGE(1, 32);
  int cur = 0;
  const int nsteps = DM / 32;
#pragma unroll 1
  for (int j = 0; j < nsteps; ++j) {
    if (j + 1 < nsteps) {
      if constexpr (TM == 128) asm volatile("s_waitcnt vmcnt(4)" ::: "memory");
      else                     asm volatile("s_waitcnt vmcnt(3)" ::: "memory");
    } else {
      asm volatile("s_waitcnt vmcnt(0)" ::: "memory");
    }
    __builtin_amdgcn_s_barrier();
    __builtin_amdgcn_sched_barrier(0);
    if (j + 2 < nsteps) {
      int nb = cur + 2; if (nb >= 3) nb -= 3;
      GSTAGE(nb, (j + 2) * 32);
    }

    bf16x8 fa[MF], fb[4];
#pragma unroll
    for (int m = 0; m < MF; ++m)
      fa[m] = ldbf8(&At[cur][(wr*(TM/2) + m*16 + ll)*32 + lg*8]);
#pragma unroll
    for (int n = 0; n < 4; ++n)
      fb[n] = ldbf8(&Bt[cur][(wc*64 + n*16 + ll)*32 + lg*8]);
#pragma unroll
    for (int m = 0; m < MF; ++m)
#pragma unroll
      for (int n = 0; n < 4; ++n)
        acc[m][n] = __builtin_amdgcn_mfma_f32_16x16x32_bf16(fa[m], fb[n], acc[m][n], 0, 0, 0);
    cur = (cur == 2) ? 0 : cur + 1;
  }
#undef GSTAGE

#pragma unroll
  for (int m = 0; m < MF; ++m) {
#pragma unroll
    for (int n = 0; n < 4; ++n) {
      const int gn  = col0 + wc*64 + n*16 + ll;
      const float bv = bias[gn];
      const int gm0 = row0 + wr*(TM/2) + m*16 + lg*4;
#pragma unroll
      for (int j = 0; j < 4; ++j) {
        const float v = acc[m][n][j] + bv;
        const int gm = gm0 + j;
        if (EPI == 0) {
          const int b = gm >> 11, s = gm & 2047;
          const int h = gn >> 6,  d = gn & 63;
          const size_t bh = (size_t)(b*NH + h);
          if (mat == 0)      q_out[(bh*SEQ + s)*DK + d] = f2bf(v * QSCALE);
          else if (mat == 1) k_out[(bh*SEQ + s)*DK + d] = f2bf(v);
          else               vt_out[(bh*DK + d)*SEQ + s] = f2bf(v);
        } else {
          f_out[(size_t)gm*DM + gn] = v;
        }
      }
    }
  }
}

// ---------------- flash attention v11: barrier-free per-wave pipelines ------
// grid 768 (xcd=L&7, bh=xcd*3+rr0%3, pairb=rr0/3; halves {63-p, p}).
// Block = 4 waves: h = w>>1 tile parity, r = w&1 kv half. KEY INVARIANT: each
// wave stages AND reads only its own K-half, V-half, P slab -> zero cross-wave
// LDS deps in the loop -> NO in-loop barriers. Per-wave private pipeline:
//   stage own(t+2) -> s_waitcnt vmcnt(8) (8 newest = stage(t+2); forces own
//   stage(t) + anything older done) -> compute t from own dbuf[i&1].
// Buffer reuse safe: own ds_reads of dbuf[(i+1)&1] completed at iter i-1
// (consumed by MFMAs, in-order dependence) before iter i's gl_lds overwrite.
// Block sync only at the 4-way merge epilogue (__syncthreads, drift-safe).

__device__ __forceinline__ void stage_kv_half(const u16* kp, const u16* vp, int kv0,
                                              u16* Kb, u16* Vb, int r, int lane) {
  const char* kg = (const char*)kp + (size_t)kv0 * 128;   // K rows contiguous
  const char* vg = (const char*)vp + (size_t)kv0 * 2;     // V^T d-rows stride 4096B
#pragma unroll
  for (int j = 0; j < 4; ++j) {                 // K half: rows [r*32, r*32+32)
    const int base = (r*4 + j) * 1024;
    const int a = base + lane*16;
    const int row = a >> 7;                     // 128B rows
    const int cs  = ((a >> 4) & 7) ^ (row & 7);
    gl_lds16(kg + row*128 + cs*16, (char*)Kb + base);
  }
#pragma unroll
  for (int j = 0; j < 4; ++j) {                 // V half: [64 d][32 s] block at r*4096
    const int base = j * 1024;
    const int a = base + lane*16;
    const int row = a >> 6;                     // 64B rows (d)
    const int cs  = ((a >> 4) & 3) ^ ((row >> 1) & 3);
    gl_lds16(vg + (size_t)row*4096 + r*64 + cs*16, (char*)Vb + r*4096 + base);
  }
}

__device__ __forceinline__ bf16x8 ldtileK(const u16* T, int row, int wo) {
  return ldbf8((const u16*)((const char*)T + row*128 + (wo ^ ((row & 7) << 4))));
}
__device__ __forceinline__ bf16x8 ldtileV(const u16* T, int r, int row, int lg) {
  const int c = lg ^ ((row >> 1) & 3);
  return ldbf8((const u16*)((const char*)T + r*4096 + row*64 + c*16));
}

__global__ __launch_bounds__(256, 2) void attn_fwd(
    const u16* __restrict__ qb, const u16* __restrict__ kb,
    const u16* __restrict__ vtb, u16* __restrict__ attb)
{
  __shared__ u16 KVb[2][2][2][64*64];           // [parity][dbuf][K|V] = 64KB
  __shared__ __align__(16) char arena[9472];    // P repack (loop) / merge buf
  const int L = blockIdx.x;
  const int xcd = L & 7, rr0 = L >> 3;
  const int bh = xcd * 3 + (rr0 % 3);
  const int pairb = rr0 / 3;                    // 0..31
  const int tid = threadIdx.x;
  const int w = tid >> 6, lane = tid & 63;
  const int h = w >> 1, r = w & 1;              // tile parity, kv half
  const int lg = lane >> 4, ll = lane & 15;
  const u16* qp = qb  + (size_t)bh * SEQ * DK;
  const u16* kp = kb  + (size_t)bh * SEQ * DK;
  const u16* vp = vtb + (size_t)bh * DK * SEQ;
  const int bb = bh / NH, hh = bh % NH;
  u16* Pl = (u16*)(arena) + w*1152;             // per-wave 2304B: [2 chunk][16 q][72B]
  float* slot = (float*)(arena) + lane*37;      // merge buf (time-shared with Pl)

#pragma unroll 1
  for (int half = 0; half < 2; ++half) {
    const int tile = half ? pairb : 63 - pairb;  // 32-row q-tile
    const int nt = (tile >> 1) + 1;              // KV tiles (causal)
    const int q0b = tile * 32;

    bf16x8 qf[2][2];
#pragma unroll
    for (int c = 0; c < 2; ++c)
#pragma unroll
      for (int d = 0; d < 2; ++d)
        qf[c][d] = ldbf8(&qp[(size_t)(q0b + c*16 + ll)*DK + d*32 + lg*8]);

    f32x4 o[2][4] = {};                          // [chunk][dt]: O[q=c*16+ll][dt*16+lg*4+j]
    float mrun[2] = {0.f, 0.f}, lrun[2] = {0.f, 0.f};

    const int nI = (nt > h) ? ((nt - h + 1) >> 1) : 0;   // own tiles t=h,h+2,..<nt
    if (nI > 0)
      stage_kv_half(kp, vp, h*64, KVb[h][0][0], KVb[h][0][1], r, lane);

#pragma unroll 1
    for (int i = 0; i < nI; ++i) {
      const int t = h + 2*i;
      if (i + 1 < nI) {
        stage_kv_half(kp, vp, (t+2)*64, KVb[h][(i+1)&1][0], KVb[h][(i+1)&1][1], r, lane);
        asm volatile("s_waitcnt vmcnt(8)" ::: "memory");   // own stage(t) done
      } else {
        asm volatile("s_waitcnt vmcnt(0)" ::: "memory");
      }
      __builtin_amdgcn_sched_barrier(0);

      const u16* Kc = KVb[h][i&1][0];
      const u16* Vc = KVb[h][i&1][1];
      const int kv0 = t * 64;

      // operand frags: own kv-half only (4 K + 4 V b128), reused across chunks
      bf16x8 Kf[2][2], Vf[4];
#pragma unroll
      for (int kt = 0; kt < 2; ++kt)
#pragma unroll
        for (int d = 0; d < 2; ++d)
          Kf[kt][d] = ldtileK(Kc, r*32 + kt*16 + ll, d*64 + lg*16);
#pragma unroll
      for (int dt = 0; dt < 4; ++dt)
        Vf[dt] = ldtileV(Vc, r, dt*16 + ll, lg);

      // S^T = K_half . Q^T : two independent chunk chains
      f32x4 st[2][2] = {};
      __builtin_amdgcn_s_setprio(1);
#pragma unroll
      for (int c = 0; c < 2; ++c)
#pragma unroll
        for (int kt = 0; kt < 2; ++kt) {
          st[c][kt] = __builtin_amdgcn_mfma_f32_16x16x32_bf16(Kf[kt][0], qf[c][0], st[c][kt], 0,0,0);
          st[c][kt] = __builtin_amdgcn_mfma_f32_16x16x32_bf16(Kf[kt][1], qf[c][1], st[c][kt], 0,0,0);
        }
      __builtin_amdgcn_s_setprio(0);

      if (t == nt - 1) {                         // diagonal: causal mask
        const int kvb = kv0 + r*32;
#pragma unroll
        for (int c = 0; c < 2; ++c)
#pragma unroll
          for (int kt = 0; kt < 2; ++kt)
#pragma unroll
            for (int j = 0; j < 4; ++j)
              if (kvb + kt*16 + lg*4 + j > q0b + c*16 + ll) st[c][kt][j] = -1e30f;
      }

      float lm[2];
#pragma unroll
      for (int c = 0; c < 2; ++c)
        lm[c] = fmaxf(fmaxf(fmaxf(st[c][0][0], st[c][0][1]), fmaxf(st[c][0][2], st[c][0][3])),
                      fmaxf(fmaxf(st[c][1][0], st[c][1][1]), fmaxf(st[c][1][2], st[c][1][3])));

      if (!__all(fmaxf(lm[0] - mrun[0], lm[1] - mrun[1]) <= 8.f)) {   // rare
#pragma unroll
        for (int c = 0; c < 2; ++c) {
          float mt = lm[c];
          mt = fmaxf(mt, __shfl_xor(mt, 16));
          mt = fmaxf(mt, __shfl_xor(mt, 32));
          const float mn = fmaxf(mrun[c], mt);
          const float sc = exp2f(mrun[c] - mn);
          lrun[c] *= sc;
#pragma unroll
          for (int dt = 0; dt < 4; ++dt)
#pragma unroll
            for (int j = 0; j < 4; ++j)
              o[c][dt][j] *= sc;
          mrun[c] = mn;
        }
      }

      bf16x8 pb[2];
#pragma unroll
      for (int c = 0; c < 2; ++c) {
        float psum = 0.f;
#pragma unroll
        for (int kt = 0; kt < 2; ++kt) {
          const float e0 = exp2f(st[c][kt][0] - mrun[c]);
          const float e1 = exp2f(st[c][kt][1] - mrun[c]);
          const float e2 = exp2f(st[c][kt][2] - mrun[c]);
          const float e3 = exp2f(st[c][kt][3] - mrun[c]);
          psum += (e0 + e1) + (e2 + e3);
          *(uint2*)&Pl[c*576 + ll*36 + kt*16 + lg*4] =
              make_uint2(cvtpk(e0, e1), cvtpk(e2, e3));
        }
        lrun[c] += psum;
        pb[c] = ldbf8(&Pl[c*576 + ll*36 + lg*8]);   // P[q=c*16+ll][kv lg*8..+7]
      }

      // O^T += V_half . P^T (K-dim = 32 = own kv half)
      __builtin_amdgcn_s_setprio(1);
#pragma unroll
      for (int c = 0; c < 2; ++c)
#pragma unroll
        for (int dt = 0; dt < 4; ++dt)
          o[c][dt] = __builtin_amdgcn_mfma_f32_16x16x32_bf16(Vf[dt], pb[c], o[c][dt], 0,0,0);
      __builtin_amdgcn_s_setprio(0);
    }

    // per-wave row totals (sum lg partials of own kv subset)
    float lt[2];
#pragma unroll
    for (int c = 0; c < 2; ++c) {
      lt[c] = lrun[c];
      lt[c] += __shfl_xor(lt[c], 16);
      lt[c] += __shfl_xor(lt[c], 32);
    }

    // 4-way merge: (w0 <- w1), (w2 <- w3), (w0 <- w2), f32 exact
#define PUBLISH() do {                                                   \
      _Pragma("unroll")                                                  \
      for (int c = 0; c < 2; ++c)                                        \
        _Pragma("unroll")                                                \
        for (int dt = 0; dt < 4; ++dt)                                   \
          _Pragma("unroll")                                              \
          for (int j = 0; j < 4; ++j)                                    \
            slot[c*16 + dt*4 + j] = o[c][dt][j];                         \
      slot[32] = mrun[0]; slot[33] = mrun[1];                            \
      slot[34] = lt[0];   slot[35] = lt[1];                              \
    } while (0)
#define MERGE() do {                                                     \
      _Pragma("unroll")                                                  \
      for (int c = 0; c < 2; ++c) {                                      \
        const float mB = slot[32 + c], lB = slot[34 + c];                \
        const float ms = fmaxf(mrun[c], mB);                             \
        const float sA = exp2f(mrun[c] - ms), sB = exp2f(mB - ms);       \
        _Pragma("unroll")                                                \
        for (int dt = 0; dt < 4; ++dt)                                   \
          _Pragma("unroll")                                              \
          for (int j = 0; j < 4; ++j)                                    \
            o[c][dt][j] = o[c][dt][j]*sA + slot[c*16 + dt*4 + j]*sB;     \
        lt[c] = lt[c]*sA + lB*sB;                                        \
        mrun[c] = ms;                                                    \
      }                                                                  \
    } while (0)

    __syncthreads();                             // all waves done; arena free
    if (w == 1) PUBLISH();
    __syncthreads();
    if (w == 0) MERGE();
    __syncthreads();                             // w0 reads done before w3 writes
    if (w == 3) PUBLISH();
    __syncthreads();
    if (w == 2) MERGE();
    __syncthreads();
    if (w == 2) PUBLISH();
    __syncthreads();
    if (w == 0) {
      MERGE();
#pragma unroll
      for (int c = 0; c < 2; ++c) {
        const float li = 1.0f / lt[c];
        u16* orow = &attb[(size_t)(bb*SEQ + q0b + c*16 + ll)*DM + hh*64];
#pragma unroll
        for (int dt = 0; dt < 4; ++dt) {
          ushort4 rw;
          rw.x = f2bf(o[c][dt][0] * li);
          rw.y = f2bf(o[c][dt][1] * li);
          rw.z = f2bf(o[c][dt][2] * li);
          rw.w = f2bf(o[c][dt][3] * li);
          *(ushort4*)&orow[dt*16 + lg*4] = rw;
        }
      }
    }
    __syncthreads();                             // arena + KV bufs free for next half
#undef PUBLISH
#undef MERGE
  }
}

// ---------------- launch ----------------
extern "C" void kernel_launch(void* const* d_in, const int* in_sizes, int n_in,
                              void* d_out, int out_size, void* d_ws, size_t ws_size,
                              hipStream_t stream) {
  const float* x  = (const float*)d_in[0];
  const float* wq = (const float*)d_in[1];
  const float* bq = (const float*)d_in[2];
  const float* wk = (const float*)d_in[3];
  const float* bk = (const float*)d_in[4];
  const float* wv = (const float*)d_in[5];
  const float* bv = (const float*)d_in[6];
  const float* wo = (const float*)d_in[7];
  const float* bo = (const float*)d_in[8];
  float* out = (float*)d_out;

  char* ws = (char*)d_ws;
  u16* xb   = (u16*)(ws);               // [4096][768]
  u16* wqb  = (u16*)(ws + 6291456);     // [768][768] x4 contiguous
  u16* wkb  = (u16*)(ws + 7471104);
  u16* wvb  = (u16*)(ws + 8650752);
  u16* wob  = (u16*)(ws + 9830400);
  u16* qb   = (u16*)(ws + 11010048);    // [24][2048][64] scaled
  u16* kb   = (u16*)(ws + 17301504);    // [24][2048][64]
  u16* vtb  = (u16*)(ws + 23592960);    // [24][64][2048]
  u16* attb = (u16*)(ws + 29884416);    // [4096][768]

  const int nx4 = MROWS*DM/4;
  const int nw4 = DM*DM/4;
  cvt_bf16<<<(nx4+255)/256, 256, 0, stream>>>(x, xb, nx4);
  cvt_w4<<<(4*nw4)/256, 256, 0, stream>>>(wq, wk, wv, wo, wqb, nw4);

  gemm_bt<0,128><<<576, 256, 0, stream>>>(xb, wqb, wkb, wvb, bq, bk, bv,
                                          qb, kb, vtb, nullptr);
  attn_fwd<<<768, 256, 0, stream>>>(qb, kb, vtb, attb);
  gemm_bt<1,64><<<384, 256, 0, stream>>>(attb, wob, nullptr, nullptr, bo, nullptr, nullptr,
                                         nullptr, nullptr, nullptr, out);
}